// Round 2
// baseline (363.095 us; speedup 1.0000x reference)
//
#include <hip/hip_runtime.h>
#include <hip/hip_bf16.h>

#define NROWS 8192
#define DDIM  512

typedef __bf16 bf16x8 __attribute__((ext_vector_type(8)));
typedef float  f32x4  __attribute__((ext_vector_type(4)));

__device__ __forceinline__ void gload_lds16(const void* g, void* l) {
    __builtin_amdgcn_global_load_lds((const __attribute__((address_space(1))) void*)g,
                                     (__attribute__((address_space(3))) void*)l,
                                     16, 0, 0);
}

// Kernel 1: per-row mu (f32 exact), d = softplus(.)+1e-8 (f32 exact), and x -> bf16.
// One wave per row; lane handles 8 contiguous k.
__global__ __launch_bounds__(256) void prep_kernel(
    const float* __restrict__ x,
    const float* __restrict__ mu_k,
    const float* __restrict__ var_k,
    const float* __restrict__ mu_b,
    const float* __restrict__ var_b,
    float* __restrict__ mu_out,
    float* __restrict__ d_vec,
    __hip_bfloat16* __restrict__ xb)
{
    const int lane = threadIdx.x & 63;
    const int row  = blockIdx.x * 4 + (threadIdx.x >> 6);
    const int k0   = lane * 8;

    const float4* xr = reinterpret_cast<const float4*>(x + (size_t)row * DDIM + k0);
    float4 a = xr[0];
    float4 b = xr[1];
    const float* mk = mu_k + k0;
    const float* vk = var_k + k0;

    float dm = a.x*mk[0] + a.y*mk[1] + a.z*mk[2] + a.w*mk[3]
             + b.x*mk[4] + b.y*mk[5] + b.z*mk[6] + b.w*mk[7];
    float dv = a.x*vk[0] + a.y*vk[1] + a.z*vk[2] + a.w*vk[3]
             + b.x*vk[4] + b.y*vk[5] + b.z*vk[6] + b.w*vk[7];

    union { __hip_bfloat16 h[8]; uint4 u; } pk;
    pk.h[0] = __float2bfloat16(a.x);
    pk.h[1] = __float2bfloat16(a.y);
    pk.h[2] = __float2bfloat16(a.z);
    pk.h[3] = __float2bfloat16(a.w);
    pk.h[4] = __float2bfloat16(b.x);
    pk.h[5] = __float2bfloat16(b.y);
    pk.h[6] = __float2bfloat16(b.z);
    pk.h[7] = __float2bfloat16(b.w);
    *reinterpret_cast<uint4*>(xb + (size_t)row * DDIM + k0) = pk.u;

    #pragma unroll
    for (int off = 32; off; off >>= 1) {
        dm += __shfl_xor(dm, off);
        dv += __shfl_xor(dv, off);
    }
    if (lane == 0) {
        mu_out[row] = dm + mu_b[0];
        float z = dv + var_b[0];
        // stable softplus == log1p(exp(z))
        d_vec[row] = fmaxf(z, 0.0f) + log1pf(expf(-fabsf(z))) + 1e-8f;
    }
}

// Kernel 2: cov = s * Xb @ Xb^T with diagonal = d_vec.
// 128x128 tile, BK=64, 4 waves (2x2), 16x16x32 bf16 MFMA, global_load_lds staging.
__global__ __launch_bounds__(256) void syrk_kernel(
    const __hip_bfloat16* __restrict__ xb,
    const float* __restrict__ d_vec,
    const float* __restrict__ rho_k,
    float* __restrict__ cov)
{
    __shared__ __align__(16) __hip_bfloat16 As[128 * 64];
    __shared__ __align__(16) __hip_bfloat16 Bs[128 * 64];

    const int tid  = threadIdx.x;
    const int lane = tid & 63;
    const int w    = tid >> 6;
    const int wr   = w >> 1, wc = w & 1;
    const size_t arow0 = (size_t)blockIdx.x * 128;
    const size_t brow0 = (size_t)blockIdx.y * 128;

    f32x4 acc[4][4] = {};

    const int srow = lane >> 3;          // 0..7 within the 8-row chunk a wave stages
    const int scol = (lane & 7) * 8;     // bf16 col within the 64-wide K slab

    for (int kt = 0; kt < DDIM; kt += 64) {
        #pragma unroll
        for (int i = 0; i < 4; ++i) {
            const int loff = i * 4096 + w * 1024;     // byte offset in LDS tile
            const int row  = i * 32 + w * 8 + srow;   // tile row this lane sources
            gload_lds16(xb + (arow0 + row) * DDIM + kt + scol, (char*)As + loff);
            gload_lds16(xb + (brow0 + row) * DDIM + kt + scol, (char*)Bs + loff);
        }
        __syncthreads();

        #pragma unroll
        for (int ks = 0; ks < 2; ++ks) {
            bf16x8 af[4], bfr[4];
            const int cb = ks * 64 + (lane >> 4) * 16;   // byte col offset (k)
            #pragma unroll
            for (int m = 0; m < 4; ++m) {
                const int r = wr * 64 + m * 16 + (lane & 15);
                af[m] = *reinterpret_cast<const bf16x8*>((const char*)As + r * 128 + cb);
            }
            #pragma unroll
            for (int n = 0; n < 4; ++n) {
                const int r = wc * 64 + n * 16 + (lane & 15);
                bfr[n] = *reinterpret_cast<const bf16x8*>((const char*)Bs + r * 128 + cb);
            }
            #pragma unroll
            for (int m = 0; m < 4; ++m)
                #pragma unroll
                for (int n = 0; n < 4; ++n)
                    acc[m][n] = __builtin_amdgcn_mfma_f32_16x16x32_bf16(
                        af[m], bfr[n], acc[m][n], 0, 0, 0);
        }
        __syncthreads();
    }

    const float s = rho_k[0];
    const size_t gr0 = arow0 + wr * 64 + (lane >> 4) * 4;  // C row base for reg 0
    const size_t gc0 = brow0 + wc * 64 + (lane & 15);      // C col
    #pragma unroll
    for (int m = 0; m < 4; ++m) {
        #pragma unroll
        for (int n = 0; n < 4; ++n) {
            const size_t col = gc0 + n * 16;
            #pragma unroll
            for (int r = 0; r < 4; ++r) {
                const size_t row = gr0 + m * 16 + r;
                float v = acc[m][n][r] * s;
                if (row == col) v = d_vec[row];
                cov[row * (size_t)NROWS + col] = v;
            }
        }
    }
}

extern "C" void kernel_launch(void* const* d_in, const int* in_sizes, int n_in,
                              void* d_out, int out_size, void* d_ws, size_t ws_size,
                              hipStream_t stream) {
    const float* x     = (const float*)d_in[0];
    const float* mu_k  = (const float*)d_in[1];
    const float* rho_k = (const float*)d_in[2];
    const float* var_k = (const float*)d_in[3];
    const float* mu_b  = (const float*)d_in[4];
    const float* var_b = (const float*)d_in[5];

    float* out    = (float*)d_out;
    float* mu_out = out;           // [8192]
    float* cov    = out + NROWS;   // [8192 * 8192]

    __hip_bfloat16* xb = (__hip_bfloat16*)d_ws;                       // 8 MiB
    float* d_vec = (float*)((char*)d_ws + (size_t)NROWS * DDIM * 2);  // 32 KiB

    prep_kernel<<<NROWS / 4, 256, 0, stream>>>(x, mu_k, var_k, mu_b, var_b,
                                               mu_out, d_vec, xb);

    dim3 grid(64, 64);
    syrk_kernel<<<grid, 256, 0, stream>>>(xb, d_vec, rho_k, cov);
}

// Round 3
// 335.044 us; speedup vs baseline: 1.0837x; 1.0837x over previous
//
#include <hip/hip_runtime.h>
#include <hip/hip_bf16.h>

#define NROWS 8192
#define DDIM  512

typedef __bf16 bf16x8 __attribute__((ext_vector_type(8)));
typedef float  f32x4  __attribute__((ext_vector_type(4)));

__device__ __forceinline__ void gload_lds16(const void* g, void* l) {
    __builtin_amdgcn_global_load_lds((const __attribute__((address_space(1))) void*)g,
                                     (__attribute__((address_space(3))) void*)l,
                                     16, 0, 0);
}

// Kernel 1: per-row mu (f32 exact), d = softplus(.)+1e-8 (f32 exact), and x -> bf16.
__global__ __launch_bounds__(256) void prep_kernel(
    const float* __restrict__ x,
    const float* __restrict__ mu_k,
    const float* __restrict__ var_k,
    const float* __restrict__ mu_b,
    const float* __restrict__ var_b,
    float* __restrict__ mu_out,
    float* __restrict__ d_vec,
    __hip_bfloat16* __restrict__ xb)
{
    const int lane = threadIdx.x & 63;
    const int row  = blockIdx.x * 4 + (threadIdx.x >> 6);
    const int k0   = lane * 8;

    const float4* xr = reinterpret_cast<const float4*>(x + (size_t)row * DDIM + k0);
    float4 a = xr[0];
    float4 b = xr[1];
    const float* mk = mu_k + k0;
    const float* vk = var_k + k0;

    float dm = a.x*mk[0] + a.y*mk[1] + a.z*mk[2] + a.w*mk[3]
             + b.x*mk[4] + b.y*mk[5] + b.z*mk[6] + b.w*mk[7];
    float dv = a.x*vk[0] + a.y*vk[1] + a.z*vk[2] + a.w*vk[3]
             + b.x*vk[4] + b.y*vk[5] + b.z*vk[6] + b.w*vk[7];

    union { __hip_bfloat16 h[8]; uint4 u; } pk;
    pk.h[0] = __float2bfloat16(a.x);
    pk.h[1] = __float2bfloat16(a.y);
    pk.h[2] = __float2bfloat16(a.z);
    pk.h[3] = __float2bfloat16(a.w);
    pk.h[4] = __float2bfloat16(b.x);
    pk.h[5] = __float2bfloat16(b.y);
    pk.h[6] = __float2bfloat16(b.z);
    pk.h[7] = __float2bfloat16(b.w);
    *reinterpret_cast<uint4*>(xb + (size_t)row * DDIM + k0) = pk.u;

    #pragma unroll
    for (int off = 32; off; off >>= 1) {
        dm += __shfl_xor(dm, off);
        dv += __shfl_xor(dv, off);
    }
    if (lane == 0) {
        mu_out[row] = dm + mu_b[0];
        float z = dv + var_b[0];
        d_vec[row] = fmaxf(z, 0.0f) + log1pf(expf(-fabsf(z))) + 1e-8f;
    }
}

// Kernel 2: cov = s * Xb @ Xb^T, symmetric: only upper-triangle tile-blocks
// computed (2080 of 4096); mirror tile written via LDS transpose. Diagonal
// replaced by d_vec. 128x128 tile, BK=64, 4 waves, 16x16x32 bf16 MFMA.
__global__ __launch_bounds__(256) void syrk_kernel(
    const __hip_bfloat16* __restrict__ xb,
    const float* __restrict__ d_vec,
    const float* __restrict__ rho_k,
    float* __restrict__ cov)
{
    // 34048 B: overlays {As,Bs} (32768 B) during K-loop, T[64][133] f32 after.
    __shared__ __align__(16) char smem[64 * 133 * 4];
    __hip_bfloat16* As = reinterpret_cast<__hip_bfloat16*>(smem);
    __hip_bfloat16* Bs = reinterpret_cast<__hip_bfloat16*>(smem + 16384);
    float* T = reinterpret_cast<float*>(smem);

    // Triangular decode: bid -> (bi, bj), bi <= bj, 64 row-blocks.
    // s(i) = i*64 - i*(i-1)/2
    const int bid = blockIdx.x;
    int bi = (int)(64.5f - sqrtf(64.5f * 64.5f - 2.0f * (float)bid));
    if (bi < 0) bi = 0;
    if (bi > 63) bi = 63;
    while ((bi + 1) * 64 - ((bi + 1) * bi) / 2 <= bid) ++bi;
    while (bi * 64 - (bi * (bi - 1)) / 2 > bid) --bi;
    const int bj = bi + (bid - (bi * 64 - (bi * (bi - 1)) / 2));

    const int tid  = threadIdx.x;
    const int lane = tid & 63;
    const int w    = tid >> 6;
    const int wr   = w >> 1, wc = w & 1;
    const size_t arow0 = (size_t)bi * 128;   // tile rows
    const size_t brow0 = (size_t)bj * 128;   // tile cols

    f32x4 acc[4][4] = {};

    const int srow = lane >> 3;
    const int scol = (lane & 7) * 8;

    for (int kt = 0; kt < DDIM; kt += 64) {
        #pragma unroll
        for (int i = 0; i < 4; ++i) {
            const int loff = i * 4096 + w * 1024;
            const int row  = i * 32 + w * 8 + srow;
            gload_lds16(xb + (arow0 + row) * DDIM + kt + scol, (char*)As + loff);
            gload_lds16(xb + (brow0 + row) * DDIM + kt + scol, (char*)Bs + loff);
        }
        __syncthreads();

        #pragma unroll
        for (int ks = 0; ks < 2; ++ks) {
            bf16x8 af[4], bfr[4];
            const int cb = ks * 64 + (lane >> 4) * 16;
            #pragma unroll
            for (int m = 0; m < 4; ++m) {
                const int r = wr * 64 + m * 16 + (lane & 15);
                af[m] = *reinterpret_cast<const bf16x8*>((const char*)As + r * 128 + cb);
            }
            #pragma unroll
            for (int n = 0; n < 4; ++n) {
                const int r = wc * 64 + n * 16 + (lane & 15);
                bfr[n] = *reinterpret_cast<const bf16x8*>((const char*)Bs + r * 128 + cb);
            }
            #pragma unroll
            for (int m = 0; m < 4; ++m)
                #pragma unroll
                for (int n = 0; n < 4; ++n)
                    acc[m][n] = __builtin_amdgcn_mfma_f32_16x16x32_bf16(
                        af[m], bfr[n], acc[m][n], 0, 0, 0);
        }
        __syncthreads();
    }

    const float s = rho_k[0];
    const bool isDiag = (bi == bj);
    const size_t gr0 = arow0 + wr * 64 + (lane >> 4) * 4;
    const size_t gc0 = brow0 + wc * 64 + (lane & 15);

    // Direct write: cov[arow0+r][brow0+c] (upper-triangle tile)
    if (isDiag) {
        #pragma unroll
        for (int m = 0; m < 4; ++m)
            #pragma unroll
            for (int n = 0; n < 4; ++n) {
                const size_t col = gc0 + n * 16;
                #pragma unroll
                for (int r = 0; r < 4; ++r) {
                    const size_t row = gr0 + m * 16 + r;
                    float v = acc[m][n][r] * s;
                    if (row == col) v = d_vec[row];
                    cov[row * (size_t)NROWS + col] = v;
                }
            }
    } else {
        #pragma unroll
        for (int m = 0; m < 4; ++m)
            #pragma unroll
            for (int n = 0; n < 4; ++n) {
                const size_t col = gc0 + n * 16;
                #pragma unroll
                for (int r = 0; r < 4; ++r) {
                    const size_t row = gr0 + m * 16 + r;
                    cov[row * (size_t)NROWS + col] = acc[m][n][r] * s;
                }
            }

        // Mirror write: cov[brow0+c][arow0+r] via LDS transpose, two 64-row halves.
        #pragma unroll
        for (int h = 0; h < 2; ++h) {
            __syncthreads();
            if (wr == h) {
                // T[r'][c]: r' = tile row - h*64 in [0,64), c in [0,128)
                #pragma unroll
                for (int m = 0; m < 4; ++m)
                    #pragma unroll
                    for (int n = 0; n < 4; ++n) {
                        const int c = wc * 64 + n * 16 + (lane & 15);
                        #pragma unroll
                        for (int r = 0; r < 4; ++r) {
                            const int rp = m * 16 + (lane >> 4) * 4 + r;
                            T[rp * 133 + c] = acc[m][n][r] * s;
                        }
                    }
            }
            __syncthreads();
            // 2048 float4 chunks: chunk = it*256 + tid; c = chunk>>4, r0 = (chunk&15)*4
            #pragma unroll
            for (int it = 0; it < 8; ++it) {
                const int chunk = it * 256 + tid;
                const int c  = chunk >> 4;
                const int r0 = (chunk & 15) * 4;
                float4 v;
                v.x = T[(r0 + 0) * 133 + c];
                v.y = T[(r0 + 1) * 133 + c];
                v.z = T[(r0 + 2) * 133 + c];
                v.w = T[(r0 + 3) * 133 + c];
                *reinterpret_cast<float4*>(
                    &cov[(brow0 + c) * (size_t)NROWS + arow0 + h * 64 + r0]) = v;
            }
        }
    }
}

extern "C" void kernel_launch(void* const* d_in, const int* in_sizes, int n_in,
                              void* d_out, int out_size, void* d_ws, size_t ws_size,
                              hipStream_t stream) {
    const float* x     = (const float*)d_in[0];
    const float* mu_k  = (const float*)d_in[1];
    const float* rho_k = (const float*)d_in[2];
    const float* var_k = (const float*)d_in[3];
    const float* mu_b  = (const float*)d_in[4];
    const float* var_b = (const float*)d_in[5];

    float* out    = (float*)d_out;
    float* mu_out = out;           // [8192]
    float* cov    = out + NROWS;   // [8192 * 8192]

    __hip_bfloat16* xb = (__hip_bfloat16*)d_ws;                       // 8 MiB
    float* d_vec = (float*)((char*)d_ws + (size_t)NROWS * DDIM * 2);  // 32 KiB

    prep_kernel<<<NROWS / 4, 256, 0, stream>>>(x, mu_k, var_k, mu_b, var_b,
                                               mu_out, d_vec, xb);

    syrk_kernel<<<2080, 256, 0, stream>>>(xb, d_vec, rho_k, cov);
}